// Round 10
// baseline (263.567 us; speedup 1.0000x reference)
//
#include <hip/hip_runtime.h>
#include <math.h>

// Problem constants (from reference)
#define NN   20000            // nodes
#define NE   320000           // edges (before self loops)
#define NG   64               // graphs
#define INF_ 6                // input features
#define EDF  2                // edge feature dim
#define NH   4                // heads
#define FD   64               // per-head dim
#define HF   256              // NH*FD
#define FCD  64               // pre-pool MLP dim
#define NCD  2                // classes
#define CAP  64               // fixed slots per node; P(deg>=64 | Poisson(16)) ~ 1e-19

// k_init block partition: zero-cnt | zero-gpool | wconv | l0
#define ZB   ((NN + 255) / 256)   // 79
#define WCB  512
#define L0B  ((NN + 3) / 4)       // 5000

typedef short bf16x8 __attribute__((ext_vector_type(8)));   // 8 bf16 (4 VGPRs)
typedef float f32x4  __attribute__((ext_vector_type(4)));   // MFMA acc
typedef float f32x2  __attribute__((ext_vector_type(2)));   // packed fp32 (v_pk_*_f32)

// bf16 helpers (RNE)
static __device__ __forceinline__ unsigned short f2bf(float f) {
  unsigned u = __float_as_uint(f);
  unsigned r = 0x7fffu + ((u >> 16) & 1u);
  return (unsigned short)((u + r) >> 16);
}
static __device__ __forceinline__ float4 bf2f4(uint2 p) {
  float4 v;
  v.x = __uint_as_float(p.x << 16);
  v.y = __uint_as_float(p.x & 0xffff0000u);
  v.z = __uint_as_float(p.y << 16);
  v.w = __uint_as_float(p.y & 0xffff0000u);
  return v;
}
static __device__ __forceinline__ f32x2 bflo2(unsigned u) {
  f32x2 v;
  v.x = __uint_as_float(u << 16);
  v.y = __uint_as_float(u & 0xffff0000u);
  return v;
}
static __device__ __forceinline__ f32x2 lky(f32x2 v) {       // leaky_relu 0.2, packed
  return __builtin_elementwise_max(v, v * 0.2f);
}

// ---- DPP row reduction: 1 issue slot/stage (v_add_f32_dpp) vs 2 for shfl_xor
// (ds_swizzle + v_add), VALU-forward latency instead of ~30cy ds latency.
// Measured R8: k_agg 47.5 -> ~44.5us, total 266.9 -> 257.8.
template <int CTRL>
static __device__ __forceinline__ float dppadd(float v) {
  int m = __builtin_amdgcn_update_dpp(0, __float_as_int(v), CTRL, 0xf, 0xf, true);
  return v + __int_as_float(m);
}
static __device__ __forceinline__ float row_sum16(float t) {
  t = dppadd<0xB1>(t);    // xor 1 (quad_perm)
  t = dppadd<0x4E>(t);    // xor 2 (quad_perm)
  t = dppadd<0x124>(t);   // +rot 4 within row
  t = dppadd<0x128>(t);   // +rot 8 within row
  return t;
}

// ---------------- init: zero cnt | zero gpool+gcnt | wconv | l0_transform ----------------

__global__ __launch_bounds__(256) void k_init(
    int* __restrict__ cnt, float* __restrict__ gpool, int* __restrict__ gcnt,
    const float* __restrict__ Wl1, const float* __restrict__ Wr1,
    unsigned short* __restrict__ Wsw,
    const float* __restrict__ x,
    const float* __restrict__ Wl0, const float* __restrict__ bl0,
    const float* __restrict__ Wr0, const float* __restrict__ br0,
    unsigned short* __restrict__ xlb, unsigned short* __restrict__ xrb) {
  int b = blockIdx.x;
  int t = threadIdx.x;
  if (b < ZB) {
    int i = b * 256 + t;
    if (i < NN) cnt[i] = 0;
  } else if (b == ZB) {
    for (int i = t; i < NG * FCD; i += 256) gpool[i] = 0.f;
    if (t < NG) gcnt[t] = 0;
  } else if (b < ZB + 1 + WCB) {
    // ---- weight convert into B-fragment-swizzled order ----
    int id = (b - ZB - 1) * 256 + t;              // 0..131071
    int j = id & 7, lane = (id >> 3) & 63, kk8 = (id >> 9) & 7, ntg = id >> 12;
    int n = ntg * 16 + (lane & 15);
    int k = kk8 * 32 + (lane >> 4) * 8 + j;
    float v = (n < 256) ? Wl1[k * 256 + n] : Wr1[k * 256 + (n - 256)];
    Wsw[id] = f2bf(v);
  } else {
    // ---- layer-0 node transforms (K=6), 4 nodes/block ----
    int w = t >> 6, lane = t & 63;
    int n = (b - ZB - 1 - WCB) * 4 + w;
    if (n >= NN) return;
    int cb = lane << 2;
    float4 al = *(const float4*)&bl0[cb];
    float4 ar = *(const float4*)&br0[cb];
#pragma unroll
    for (int k = 0; k < INF_; ++k) {
      float xv = x[n * INF_ + k];
      float4 wl = *(const float4*)&Wl0[k * HF + cb];
      float4 wr = *(const float4*)&Wr0[k * HF + cb];
      al.x = fmaf(xv, wl.x, al.x); al.y = fmaf(xv, wl.y, al.y);
      al.z = fmaf(xv, wl.z, al.z); al.w = fmaf(xv, wl.w, al.w);
      ar.x = fmaf(xv, wr.x, ar.x); ar.y = fmaf(xv, wr.y, ar.y);
      ar.z = fmaf(xv, wr.z, ar.z); ar.w = fmaf(xv, wr.w, ar.w);
    }
    uint2 pk;
    pk.x = (unsigned)f2bf(al.x) | ((unsigned)f2bf(al.y) << 16);
    pk.y = (unsigned)f2bf(al.z) | ((unsigned)f2bf(al.w) << 16);
    *(uint2*)&xlb[(size_t)n * HF + cb] = pk;
    uint2 pr;
    pr.x = (unsigned)f2bf(ar.x) | ((unsigned)f2bf(ar.y) << 16);
    pr.y = (unsigned)f2bf(ar.z) | ((unsigned)f2bf(ar.w) << 16);
    *(uint2*)&xrb[(size_t)n * HF + cb] = pr;
  }
}

// ---------------- fused count+scatter into fixed-capacity buckets ----------------

__global__ void k_scatter(const int* __restrict__ ei, const float* __restrict__ ea,
                          int* __restrict__ cnt, uint2* __restrict__ rec) {
  int i = blockIdx.x * blockDim.x + threadIdx.x;
  if (i >= NE) return;
  int s = ei[i], d = ei[NE + i];
  float2 a = *(const float2*)&ea[2 * i];
  int pos = atomicAdd(&cnt[d], 1);
  if (pos < CAP)
    rec[(size_t)d * CAP + pos] = make_uint2((unsigned)(s * 512),
                                            (unsigned)f2bf(a.x) | ((unsigned)f2bf(a.y) << 16));
}

// ---------------- layer-1 transforms via MFMA ----------------

__global__ __launch_bounds__(256) void k_l1_mfma(
    const unsigned short* __restrict__ x1b,   // [NN][256] bf16
    const unsigned short* __restrict__ Wsw,   // swizzled, 256 KB
    const float* __restrict__ bl, const float* __restrict__ br,
    unsigned short* __restrict__ xlb, unsigned short* __restrict__ xrb) {
  __shared__ unsigned short so[64][264];      // 33792 B bf16 output staging (+8 pad)
  int t = threadIdx.x;
  int row0 = blockIdx.x * 64;
  int w = t >> 6, lane = t & 63;
  int quad = lane >> 4, ln = lane & 15;
  int y = blockIdx.y;                         // 0..1
  const float* bias = y ? br : bl;
  unsigned short* dst = y ? xrb : xlb;

  int arow = row0 + w * 16 + ln; if (arow >= NN) arow = NN - 1;
  const unsigned short* aptr = x1b + (size_t)arow * HF + quad * 8;

  f32x4 acc[16];
#pragma unroll
  for (int i = 0; i < 16; ++i) acc[i] = (f32x4){0.f, 0.f, 0.f, 0.f};

  for (int kk8 = 0; kk8 < 8; ++kk8) {
    bf16x8 af = *(const bf16x8*)(aptr + kk8 * 32);
#pragma unroll
    for (int nt = 0; nt < 16; ++nt) {
      bf16x8 bfr = *(const bf16x8*)&Wsw[(size_t)((((y * 16 + nt) * 8 + kk8) * 64) + lane) * 8];
      acc[nt] = __builtin_amdgcn_mfma_f32_16x16x32_bf16(af, bfr, acc[nt], 0, 0, 0);
    }
  }
  // bias + bf16 pack + LDS stage (C/D: col=ln, row=quad*4+rg)
#pragma unroll
  for (int nt = 0; nt < 16; ++nt) {
    float bv = bias[nt * 16 + ln];
#pragma unroll
    for (int rg = 0; rg < 4; ++rg)
      so[w * 16 + quad * 4 + rg][nt * 16 + ln] = f2bf(acc[nt][rg] + bv);
  }
  __syncthreads();
  // coalesced copy-out: 64 rows x 256 cols bf16, uint4 = 8 bf16, 8 per thread
#pragma unroll
  for (int i = 0; i < 8; ++i) {
    int idx = i * 256 + t;                    // 0..2047
    int row = idx >> 5, c8 = idx & 31;
    int grow = row0 + row;
    if (grow < NN)
      *(uint4*)&dst[(size_t)grow * HF + c8 * 8] = *(const uint4*)&so[row][c8 * 8];
  }
}

// ---------------- fused GATv2: one WAVE per node (R9 + exp2-fold + hoisted base) ----------------
// Issue-slot diagnosis (R7-R9, confirmed twice by measured wins): the SIMD issue
// port is the binding resource. R10: (a) fold log2e into att at load -> bare
// exp2f = single v_exp_f32 (no v_mul), consistent across main/epilogue/self-loop;
// (b) per-lane gather base xlcb = xlb + cbb hoisted -> one 64-bit add per gather.

template <bool L0>
__global__ __launch_bounds__(256) void k_agg(
    const unsigned short* __restrict__ xlb, const unsigned short* xrb_,  // no restrict: x2b aliases
    const int* __restrict__ cnt, const uint2* __restrict__ rec,
    const float* __restrict__ att, const float* __restrict__ We,
    const float* __restrict__ bias,
    const float* __restrict__ x, const float* __restrict__ proj0,
    unsigned short* __restrict__ x1bout,
    const unsigned short* __restrict__ x1bin, unsigned short* x2bout) {
  int wid = (blockIdx.x * 256 + threadIdx.x) >> 6;
  if (wid >= NN) return;
  int lane = threadIdx.x & 63;
  int n = wid;
  int cb = lane << 2;                    // channel base (0..252)
  unsigned cbb = (unsigned)(cb << 1);    // byte offset within a bf16 row

  const char* xlcb = (const char*)xlb + cbb;   // per-lane gather base (hoisted)

  int nreal = min(cnt[n], CAP);          // real incoming edges
  int lastE = nreal - 1;
  const uint2* recn = rec + (size_t)n * CAP;

  // ---- warm the record row in L1 (one coalesced load) + mean-attr contributions ----
  float a0s = 0.f, a1s = 0.f;
  if (lane < nreal) {
    uint2 r = recn[lane];
    a0s = __uint_as_float(r.y << 16);
    a1s = __uint_as_float(r.y & 0xffff0000u);
  }
  // self-row load issued early; consumed only at the tail
  uint2 ps = *(const uint2*)(xlcb + (unsigned)(n * 512));

  float4 xr4 = bf2f4(*(const uint2*)&xrb_[(size_t)n * HF + cb]);
  float4 at4 = *(const float4*)&att[cb];
  // fold log2(e) into att: t is then in the log2 domain; exp(t_nat) == exp2(t).
  const float LOG2E = 1.4426950408889634f;
  at4.x *= LOG2E; at4.y *= LOG2E; at4.z *= LOG2E; at4.w *= LOG2E;
  float4 w04 = *(const float4*)&We[cb];
  float4 w14 = *(const float4*)&We[HF + cb];
  f32x2 xrA = {xr4.x, xr4.y}, xrB = {xr4.z, xr4.w};
  f32x2 atA = {at4.x, at4.y}, atB = {at4.z, at4.w};
  f32x2 w0A = {w04.x, w04.y}, w0B = {w04.z, w04.w};
  f32x2 w1A = {w14.x, w14.y}, w1B = {w14.z, w14.w};

  f32x2 accA = {0.f, 0.f}, accB = {0.f, 0.f};
  float den = 0.f;

  // ---- guard-free main loop: full batches of 4 real edges ----
  int nfull = nreal >> 2;
  for (int bb = 0; bb < nfull; ++bb) {
    int e0 = bb << 2;
    uint4 q0 = *(const uint4*)&recn[e0];         // records e0, e0+1 (real)
    uint4 q1 = *(const uint4*)&recn[e0 + 2];     // records e0+2, e0+3 (real)
    unsigned off[4] = {q0.x, q0.z, q1.x, q1.z};
    unsigned atr[4] = {q0.y, q0.w, q1.y, q1.w};
    uint2 p4[4];
#pragma unroll
    for (int i = 0; i < 4; ++i)
      p4[i] = *(const uint2*)(xlcb + off[i]);    // no clamp: offsets valid

    float t4[4];
#pragma unroll
    for (int i = 0; i < 4; ++i) {
      float a0 = __uint_as_float(atr[i] << 16);
      float a1 = __uint_as_float(atr[i] & 0xffff0000u);
      f32x2 a0v = {a0, a0}, a1v = {a1, a1};
      f32x2 mA = a1v * w1A + xrA; mA = a0v * w0A + mA; // pk_fma chains
      f32x2 mB = a1v * w1B + xrB; mB = a0v * w0B + mB;
      mA = lky(mA + bflo2(p4[i].x));
      mB = lky(mB + bflo2(p4[i].y));
      f32x2 d = mA * atA;
      d = mB * atB + d;
      t4[i] = d.x + d.y;
    }
#pragma unroll
    for (int i = 0; i < 4; ++i) t4[i] = row_sum16(t4[i]);   // DPP, 4 indep chains
#pragma unroll
    for (int i = 0; i < 4; ++i) {
      float w = exp2f(t4[i]);                    // single v_exp_f32 (log2 domain)
      den += w;
      f32x2 wv = {w, w};
      accA = wv * bflo2(p4[i].x) + accA;         // pk_fma
      accB = wv * bflo2(p4[i].y) + accB;
    }
  }

  // ---- masked epilogue: remaining 1..3 edges (clamped indices -> real records) ----
  int rem = nreal & 3;
  if (rem) {
    int e0 = nfull << 2;
    uint2 r4[4], p4[4];
#pragma unroll
    for (int i = 0; i < 4; ++i)
      r4[i] = recn[min(e0 + i, lastE)];          // real record (duplicate past rem)
#pragma unroll
    for (int i = 0; i < 4; ++i)
      p4[i] = *(const uint2*)(xlcb + r4[i].x);

    float t4[4];
#pragma unroll
    for (int i = 0; i < 4; ++i) {
      float a0 = __uint_as_float(r4[i].y << 16);
      float a1 = __uint_as_float(r4[i].y & 0xffff0000u);
      f32x2 a0v = {a0, a0}, a1v = {a1, a1};
      f32x2 mA = a1v * w1A + xrA; mA = a0v * w0A + mA;
      f32x2 mB = a1v * w1B + xrB; mB = a0v * w0B + mB;
      mA = lky(mA + bflo2(p4[i].x));
      mB = lky(mB + bflo2(p4[i].y));
      f32x2 d = mA * atA;
      d = mB * atB + d;
      t4[i] = d.x + d.y;
    }
#pragma unroll
    for (int i = 0; i < 4; ++i) t4[i] = row_sum16(t4[i]);
#pragma unroll
    for (int i = 0; i < 4; ++i) {
      float w = (i < rem) ? exp2f(t4[i]) : 0.f;  // mask duplicates
      den += w;
      f32x2 wv = {w, w};
      accA = wv * bflo2(p4[i].x) + accA;
      accB = wv * bflo2(p4[i].y) + accB;
    }
  }

  // ---- mean-attr reduction: DPP within rows, shfl across rows (once/node) ----
  a0s = row_sum16(a0s);
  a1s = row_sum16(a1s);
  a0s += __shfl_xor(a0s, 16, 64);
  a1s += __shfl_xor(a1s, 16, 64);
  a0s += __shfl_xor(a0s, 32, 64);
  a1s += __shfl_xor(a1s, 32, 64);
  float im = 1.0f / fmaxf((float)nreal, 1.0f);
  float a0m = a0s * im, a1m = a1s * im;

  // ---- self-loop term (attrs = mean of incoming), added last ----
  f32x2 vSA = bflo2(ps.x), vSB = bflo2(ps.y);
  {
    f32x2 a0v = {a0m, a0m}, a1v = {a1m, a1m};
    f32x2 mA = a1v * w1A + xrA; mA = a0v * w0A + mA;
    f32x2 mB = a1v * w1B + xrB; mB = a0v * w0B + mB;
    mA = lky(mA + vSA);
    mB = lky(mB + vSB);
    f32x2 d = mA * atA;
    d = mB * atB + d;
    float tS = row_sum16(d.x + d.y);
    float wS = exp2f(fminf(tS, 115.f));          // clamp rescaled to log2 domain
    den += wS;
    f32x2 wv = {wS, wS};
    accA = wv * vSA + accA;
    accB = wv * vSB + accB;
  }

  float inv = 1.0f / den;
  float4 b4 = *(const float4*)&bias[cb];
  float4 o;
  o.x = fmaf(accA.x, inv, b4.x);
  o.y = fmaf(accA.y, inv, b4.y);
  o.z = fmaf(accB.x, inv, b4.z);
  o.w = fmaf(accB.y, inv, b4.w);
  o.x = (o.x > 0.f) ? o.x : expm1f(o.x);            // elu
  o.y = (o.y > 0.f) ? o.y : expm1f(o.y);
  o.z = (o.z > 0.f) ? o.z : expm1f(o.z);
  o.w = (o.w > 0.f) ? o.w : expm1f(o.w);

  if (L0) {
    f32x2 rA = {0.f, 0.f}, rB = {0.f, 0.f};
#pragma unroll
    for (int k = 0; k < INF_; ++k) {
      float xv = x[n * INF_ + k];                    // wave-uniform -> scalar load
      float4 p = *(const float4*)&proj0[k * HF + cb];
      f32x2 xvv = {xv, xv};
      f32x2 pA = {p.x, p.y}, pB = {p.z, p.w};
      rA = xvv * pA + rA;
      rB = xvv * pB + rB;
    }
    o.x += rA.x; o.y += rA.y; o.z += rB.x; o.w += rB.y;
    uint2 pk;                          // x1 kept only as bf16 (feeds MFMA + residual)
    pk.x = (unsigned)f2bf(o.x) | ((unsigned)f2bf(o.y) << 16);
    pk.y = (unsigned)f2bf(o.z) | ((unsigned)f2bf(o.w) << 16);
    *(uint2*)&x1bout[(size_t)n * HF + cb] = pk;
  } else {
    float4 x1v = bf2f4(*(const uint2*)&x1bin[(size_t)n * HF + cb]);
    o.x += x1v.x; o.y += x1v.y; o.z += x1v.z; o.w += x1v.w;
    uint2 pk;                          // x2 bf16 (feeds mean-pool; error attenuated ~17x)
    pk.x = (unsigned)f2bf(o.x) | ((unsigned)f2bf(o.y) << 16);
    pk.y = (unsigned)f2bf(o.z) | ((unsigned)f2bf(o.w) << 16);
    *(uint2*)&x2bout[(size_t)n * HF + cb] = pk;      // aliases xrb_ row n: safe (own row, after read)
  }
}

// ---------------- pre-pool MLP + graph pooling: z=elu(x2@Wp+bp); gpool += z ----------------
// R10: inner product in f32x2 pk_fma (xv.xy / xv.zw of the float4 LDS read are
// already register pairs -> no repack movs). Halves the 2048-FMA issue budget.

__global__ __launch_bounds__(256) void k_pool(
    const unsigned short* __restrict__ x2b, const float* __restrict__ Wp,
    const float* __restrict__ bp, const int* __restrict__ batch,
    float* __restrict__ gpool, int* __restrict__ gcnt) {
  __shared__ float xs[32 * HF];
  __shared__ int gid_s[32];
  int t = threadIdx.x;
  int row0 = blockIdx.x * 32;
  // stage 32 rows x 256 cols bf16 -> fp32 LDS (unpack once)
  const uint4* s4 = (const uint4*)(x2b + (size_t)row0 * HF);  // uint4 = 8 bf16
#pragma unroll
  for (int i = 0; i < 4; ++i) {
    int idx = i * 256 + t;               // 0..1023 (32*256/8)
    uint4 p = s4[idx];
    int base = idx * 8;
    float4 lo = bf2f4(make_uint2(p.x, p.y));
    float4 hi = bf2f4(make_uint2(p.z, p.w));
    *(float4*)&xs[base] = lo;
    *(float4*)&xs[base + 4] = hi;
  }
  if (t < 32) gid_s[t] = batch[row0 + t];
  __syncthreads();
  int j = t & 63, rg = t >> 6;          // thread: col j, rows rg*8..rg*8+7
  f32x2 pacc[8];
#pragma unroll
  for (int rr = 0; rr < 8; ++rr) pacc[rr] = (f32x2){0.f, 0.f};
  for (int k4 = 0; k4 < HF / 4; ++k4) {
    f32x2 w01 = {Wp[(k4 * 4 + 0) * FCD + j], Wp[(k4 * 4 + 1) * FCD + j]};
    f32x2 w23 = {Wp[(k4 * 4 + 2) * FCD + j], Wp[(k4 * 4 + 3) * FCD + j]};
#pragma unroll
    for (int rr = 0; rr < 8; ++rr) {
      float4 xv = *(const float4*)&xs[(rg * 8 + rr) * HF + k4 * 4];
      f32x2 x01 = {xv.x, xv.y}, x23 = {xv.z, xv.w};
      pacc[rr] = x01 * w01 + pacc[rr];           // v_pk_fma_f32
      pacc[rr] = x23 * w23 + pacc[rr];
    }
  }
  float b = bp[j];
  int gprev = gid_s[rg * 8];
  float run = 0.f;
  int rcnt = 0;
#pragma unroll
  for (int rr = 0; rr < 8; ++rr) {
    float a = pacc[rr].x + pacc[rr].y + b;
    float z = (a > 0.f) ? a : expm1f(a);
    int g = gid_s[rg * 8 + rr];
    if (g != gprev) {
      atomicAdd(&gpool[gprev * FCD + j], run);
      if (j == 0) atomicAdd(&gcnt[gprev], rcnt);
      run = 0.f; rcnt = 0; gprev = g;
    }
    run += z; ++rcnt;
  }
  atomicAdd(&gpool[gprev * FCD + j], run);
  if (j == 0) atomicAdd(&gcnt[gprev], rcnt);
}

// ---------------- final classifier (wave-parallel): one wave per graph ----------------

__global__ __launch_bounds__(256) void k_head(
    const float* __restrict__ gpool, const int* __restrict__ gcnt,
    const float* __restrict__ Wc, const float* __restrict__ bc,
    float* __restrict__ out) {
  int g = (blockIdx.x << 2) + (threadIdx.x >> 6);   // 0..63
  int lane = threadIdx.x & 63;
  float v = gpool[g * FCD + lane] / fmaxf((float)gcnt[g], 1.0f);
  float2 wc = *(const float2*)&Wc[lane * NCD];
  float a0 = v * wc.x, a1 = v * wc.y;
#pragma unroll
  for (int o = 32; o; o >>= 1) {
    a0 += __shfl_xor(a0, o, 64);
    a1 += __shfl_xor(a1, o, 64);
  }
  if (lane == 0) {
    float2 r = make_float2(a0 + bc[0], a1 + bc[1]);
    *(float2*)&out[g * NCD] = r;
  }
}

// ---------------- launch ----------------

extern "C" void kernel_launch(void* const* d_in, const int* in_sizes, int n_in,
                              void* d_out, int out_size, void* d_ws, size_t ws_size,
                              hipStream_t stream) {
  const float* x    = (const float*)d_in[0];
  const int*   ei   = (const int*)d_in[1];    // [2,E] int
  const float* ea   = (const float*)d_in[2];  // [E,2]
  const int*   batch= (const int*)d_in[3];
  const float* Wl0  = (const float*)d_in[4];
  const float* bl0  = (const float*)d_in[5];
  const float* Wr0  = (const float*)d_in[6];
  const float* br0  = (const float*)d_in[7];
  const float* We0  = (const float*)d_in[8];
  const float* att0 = (const float*)d_in[9];
  const float* b0   = (const float*)d_in[10];
  const float* proj0= (const float*)d_in[11];
  const float* Wl1  = (const float*)d_in[12];
  const float* bl1  = (const float*)d_in[13];
  const float* Wr1  = (const float*)d_in[14];
  const float* br1  = (const float*)d_in[15];
  const float* We1  = (const float*)d_in[16];
  const float* att1 = (const float*)d_in[17];
  const float* b1   = (const float*)d_in[18];
  const float* Wp   = (const float*)d_in[19];
  const float* bp   = (const float*)d_in[20];
  const float* Wc   = (const float*)d_in[21];
  const float* bc   = (const float*)d_in[22];
  float* out = (float*)d_out;

  // workspace layout (all 16B aligned)
  char* ws = (char*)d_ws;
  size_t off = 0;
  int*   cnt    = (int*)(ws + off);   off += (NN * 4 + 15) / 16 * 16;
  uint2* rec    = (uint2*)(ws + off); off += (size_t)NN * CAP * 8;     // 10.24 MB
  unsigned short* xlb = (unsigned short*)(ws + off); off += (size_t)NN * HF * 2;
  unsigned short* xrb = (unsigned short*)(ws + off); off += (size_t)NN * HF * 2;
  unsigned short* x1b = (unsigned short*)(ws + off); off += (size_t)NN * HF * 2;
  float* gpool  = (float*)(ws + off); off += NG * FCD * 4;
  unsigned short* Wsw = (unsigned short*)(ws + off); off += 512 * 256 * 2;
  int*   gcnt   = (int*)(ws + off);   off += (NG * 4 + 15) / 16 * 16;
  unsigned short* x2b = xrb;           // alias: safe (each wave writes only its own row, after reading it)
  (void)ws_size; (void)in_sizes; (void)n_in; (void)out_size;

  // init (zero cnt|gpool|gcnt, wconv, l0) -- one dispatch, no memsets
  k_init<<<ZB + 1 + WCB + L0B, 256, 0, stream>>>(
      cnt, gpool, gcnt, Wl1, Wr1, Wsw, x, Wl0, bl0, Wr0, br0, xlb, xrb);

  // fused count+scatter into fixed-capacity buckets (no CSR scan)
  k_scatter<<<(NE + 255) / 256, 256, 0, stream>>>(ei, ea, cnt, rec);

  // layer 0 aggregation (self-loop mean folded into warm pass)
  k_agg<true><<<(NN * 64 + 255) / 256, 256, 0, stream>>>(
      xlb, xrb, cnt, rec, att0, We0, b0, x, proj0, x1b, nullptr, nullptr);

  // layer 1 transforms via MFMA (y=0: Wl->xlb, y=1: Wr->xrb), then aggregation
  k_l1_mfma<<<dim3((NN + 63) / 64, 2), 256, 0, stream>>>(x1b, Wsw, bl1, br1, xlb, xrb);
  k_agg<false><<<(NN * 64 + 255) / 256, 256, 0, stream>>>(
      xlb, xrb, cnt, rec, att1, We1, b1, nullptr, nullptr, nullptr, x1b, x2b);

  // pre-pool MLP + pooling (also accumulates per-graph node counts), then classifier
  k_pool<<<NN / 32, 256, 0, stream>>>(x2b, Wp, bp, batch, gpool, gcnt);
  k_head<<<16, 256, 0, stream>>>(gpool, gcnt, Wc, bc, out);
}

// Round 11
// 253.451 us; speedup vs baseline: 1.0399x; 1.0399x over previous
//
#include <hip/hip_runtime.h>
#include <math.h>

// Problem constants (from reference)
#define NN   20000            // nodes
#define NE   320000           // edges (before self loops)
#define NG   64               // graphs
#define INF_ 6                // input features
#define EDF  2                // edge feature dim
#define NH   4                // heads
#define FD   64               // per-head dim
#define HF   256              // NH*FD
#define FCD  64               // pre-pool MLP dim
#define NCD  2                // classes
#define CAP  64               // fixed slots per node; P(deg>=64 | Poisson(16)) ~ 1e-19

// k_init block partition: zero-cnt | zero-gpool | wconv | l0
#define ZB   ((NN + 255) / 256)   // 79
#define WCB  512
#define L0B  ((NN + 3) / 4)       // 5000

typedef short bf16x8 __attribute__((ext_vector_type(8)));   // 8 bf16 (4 VGPRs)
typedef float f32x4  __attribute__((ext_vector_type(4)));   // MFMA acc
typedef float f32x2  __attribute__((ext_vector_type(2)));   // packed fp32 (v_pk_*_f32)

// bf16 helpers (RNE)
static __device__ __forceinline__ unsigned short f2bf(float f) {
  unsigned u = __float_as_uint(f);
  unsigned r = 0x7fffu + ((u >> 16) & 1u);
  return (unsigned short)((u + r) >> 16);
}
static __device__ __forceinline__ float4 bf2f4(uint2 p) {
  float4 v;
  v.x = __uint_as_float(p.x << 16);
  v.y = __uint_as_float(p.x & 0xffff0000u);
  v.z = __uint_as_float(p.y << 16);
  v.w = __uint_as_float(p.y & 0xffff0000u);
  return v;
}
static __device__ __forceinline__ f32x2 bflo2(unsigned u) {
  f32x2 v;
  v.x = __uint_as_float(u << 16);
  v.y = __uint_as_float(u & 0xffff0000u);
  return v;
}
static __device__ __forceinline__ f32x2 lky(f32x2 v) {       // leaky_relu 0.2, packed
  return __builtin_elementwise_max(v, v * 0.2f);
}

// ---- DPP row reduction: 1 issue slot/stage (v_add_f32_dpp) vs 2 for shfl_xor
// (ds_swizzle + v_add), VALU-forward latency instead of ~30cy ds latency.
// Measured R8: k_agg 47.5 -> ~44.5us, total 266.9 -> 257.8. R10 measured that
// exp2-fold and k_pool pk_fma were neutral-to-negative -> reverted to R9 form.
template <int CTRL>
static __device__ __forceinline__ float dppadd(float v) {
  int m = __builtin_amdgcn_update_dpp(0, __float_as_int(v), CTRL, 0xf, 0xf, true);
  return v + __int_as_float(m);
}
static __device__ __forceinline__ float row_sum16(float t) {
  t = dppadd<0xB1>(t);    // xor 1 (quad_perm)
  t = dppadd<0x4E>(t);    // xor 2 (quad_perm)
  t = dppadd<0x124>(t);   // +rot 4 within row
  t = dppadd<0x128>(t);   // +rot 8 within row
  return t;
}

// ---------------- init: zero cnt | zero gpool+gcnt | wconv | l0_transform ----------------

__global__ __launch_bounds__(256) void k_init(
    int* __restrict__ cnt, float* __restrict__ gpool, int* __restrict__ gcnt,
    const float* __restrict__ Wl1, const float* __restrict__ Wr1,
    unsigned short* __restrict__ Wsw,
    const float* __restrict__ x,
    const float* __restrict__ Wl0, const float* __restrict__ bl0,
    const float* __restrict__ Wr0, const float* __restrict__ br0,
    unsigned short* __restrict__ xlb, unsigned short* __restrict__ xrb) {
  int b = blockIdx.x;
  int t = threadIdx.x;
  if (b < ZB) {
    int i = b * 256 + t;
    if (i < NN) cnt[i] = 0;
  } else if (b == ZB) {
    for (int i = t; i < NG * FCD; i += 256) gpool[i] = 0.f;
    if (t < NG) gcnt[t] = 0;
  } else if (b < ZB + 1 + WCB) {
    // ---- weight convert into B-fragment-swizzled order ----
    int id = (b - ZB - 1) * 256 + t;              // 0..131071
    int j = id & 7, lane = (id >> 3) & 63, kk8 = (id >> 9) & 7, ntg = id >> 12;
    int n = ntg * 16 + (lane & 15);
    int k = kk8 * 32 + (lane >> 4) * 8 + j;
    float v = (n < 256) ? Wl1[k * 256 + n] : Wr1[k * 256 + (n - 256)];
    Wsw[id] = f2bf(v);
  } else {
    // ---- layer-0 node transforms (K=6), 4 nodes/block ----
    int w = t >> 6, lane = t & 63;
    int n = (b - ZB - 1 - WCB) * 4 + w;
    if (n >= NN) return;
    int cb = lane << 2;
    float4 al = *(const float4*)&bl0[cb];
    float4 ar = *(const float4*)&br0[cb];
#pragma unroll
    for (int k = 0; k < INF_; ++k) {
      float xv = x[n * INF_ + k];
      float4 wl = *(const float4*)&Wl0[k * HF + cb];
      float4 wr = *(const float4*)&Wr0[k * HF + cb];
      al.x = fmaf(xv, wl.x, al.x); al.y = fmaf(xv, wl.y, al.y);
      al.z = fmaf(xv, wl.z, al.z); al.w = fmaf(xv, wl.w, al.w);
      ar.x = fmaf(xv, wr.x, ar.x); ar.y = fmaf(xv, wr.y, ar.y);
      ar.z = fmaf(xv, wr.z, ar.z); ar.w = fmaf(xv, wr.w, ar.w);
    }
    uint2 pk;
    pk.x = (unsigned)f2bf(al.x) | ((unsigned)f2bf(al.y) << 16);
    pk.y = (unsigned)f2bf(al.z) | ((unsigned)f2bf(al.w) << 16);
    *(uint2*)&xlb[(size_t)n * HF + cb] = pk;
    uint2 pr;
    pr.x = (unsigned)f2bf(ar.x) | ((unsigned)f2bf(ar.y) << 16);
    pr.y = (unsigned)f2bf(ar.z) | ((unsigned)f2bf(ar.w) << 16);
    *(uint2*)&xrb[(size_t)n * HF + cb] = pr;
  }
}

// ---------------- fused count+scatter into fixed-capacity buckets ----------------

__global__ void k_scatter(const int* __restrict__ ei, const float* __restrict__ ea,
                          int* __restrict__ cnt, uint2* __restrict__ rec) {
  int i = blockIdx.x * blockDim.x + threadIdx.x;
  if (i >= NE) return;
  int s = ei[i], d = ei[NE + i];
  float2 a = *(const float2*)&ea[2 * i];
  int pos = atomicAdd(&cnt[d], 1);
  if (pos < CAP)
    rec[(size_t)d * CAP + pos] = make_uint2((unsigned)(s * 512),
                                            (unsigned)f2bf(a.x) | ((unsigned)f2bf(a.y) << 16));
}

// ---------------- layer-1 transforms via MFMA ----------------

__global__ __launch_bounds__(256) void k_l1_mfma(
    const unsigned short* __restrict__ x1b,   // [NN][256] bf16
    const unsigned short* __restrict__ Wsw,   // swizzled, 256 KB
    const float* __restrict__ bl, const float* __restrict__ br,
    unsigned short* __restrict__ xlb, unsigned short* __restrict__ xrb) {
  __shared__ unsigned short so[64][264];      // 33792 B bf16 output staging (+8 pad)
  int t = threadIdx.x;
  int row0 = blockIdx.x * 64;
  int w = t >> 6, lane = t & 63;
  int quad = lane >> 4, ln = lane & 15;
  int y = blockIdx.y;                         // 0..1
  const float* bias = y ? br : bl;
  unsigned short* dst = y ? xrb : xlb;

  int arow = row0 + w * 16 + ln; if (arow >= NN) arow = NN - 1;
  const unsigned short* aptr = x1b + (size_t)arow * HF + quad * 8;

  f32x4 acc[16];
#pragma unroll
  for (int i = 0; i < 16; ++i) acc[i] = (f32x4){0.f, 0.f, 0.f, 0.f};

  for (int kk8 = 0; kk8 < 8; ++kk8) {
    bf16x8 af = *(const bf16x8*)(aptr + kk8 * 32);
#pragma unroll
    for (int nt = 0; nt < 16; ++nt) {
      bf16x8 bfr = *(const bf16x8*)&Wsw[(size_t)((((y * 16 + nt) * 8 + kk8) * 64) + lane) * 8];
      acc[nt] = __builtin_amdgcn_mfma_f32_16x16x32_bf16(af, bfr, acc[nt], 0, 0, 0);
    }
  }
  // bias + bf16 pack + LDS stage (C/D: col=ln, row=quad*4+rg)
#pragma unroll
  for (int nt = 0; nt < 16; ++nt) {
    float bv = bias[nt * 16 + ln];
#pragma unroll
    for (int rg = 0; rg < 4; ++rg)
      so[w * 16 + quad * 4 + rg][nt * 16 + ln] = f2bf(acc[nt][rg] + bv);
  }
  __syncthreads();
  // coalesced copy-out: 64 rows x 256 cols bf16, uint4 = 8 bf16, 8 per thread
#pragma unroll
  for (int i = 0; i < 8; ++i) {
    int idx = i * 256 + t;                    // 0..2047
    int row = idx >> 5, c8 = idx & 31;
    int grow = row0 + row;
    if (grow < NN)
      *(uint4*)&dst[(size_t)grow * HF + c8 * 8] = *(const uint4*)&so[row][c8 * 8];
  }
}

// ---------------- fused GATv2: one WAVE per node (R9 final form) ----------------
// Session's measured-best structure. Issue-slot diagnosis (R7-R9): the SIMD issue
// port is the binding resource -- latency fixes (R5 pipeline) and occupancy fixes
// (R6 persistent) were neutral; only slot reductions moved the number:
// DPP reductions (R8, 47.5->44.5us) and guard-free main loop (R9, ->44).
// R10's exp2-fold + k_pool pk_fma measured neutral-to-negative -> reverted.

template <bool L0>
__global__ __launch_bounds__(256) void k_agg(
    const unsigned short* __restrict__ xlb, const unsigned short* xrb_,  // no restrict: x2b aliases
    const int* __restrict__ cnt, const uint2* __restrict__ rec,
    const float* __restrict__ att, const float* __restrict__ We,
    const float* __restrict__ bias,
    const float* __restrict__ x, const float* __restrict__ proj0,
    unsigned short* __restrict__ x1bout,
    const unsigned short* __restrict__ x1bin, unsigned short* x2bout) {
  int wid = (blockIdx.x * 256 + threadIdx.x) >> 6;
  if (wid >= NN) return;
  int lane = threadIdx.x & 63;
  int n = wid;
  int cb = lane << 2;                    // channel base (0..252)
  unsigned cbb = (unsigned)(cb << 1);    // byte offset within a bf16 row

  const char* xlbase = (const char*)xlb;

  int nreal = min(cnt[n], CAP);          // real incoming edges
  int lastE = nreal - 1;
  const uint2* recn = rec + (size_t)n * CAP;

  // ---- warm the record row in L1 (one coalesced load) + mean-attr contributions ----
  float a0s = 0.f, a1s = 0.f;
  if (lane < nreal) {
    uint2 r = recn[lane];
    a0s = __uint_as_float(r.y << 16);
    a1s = __uint_as_float(r.y & 0xffff0000u);
  }
  // self-row load issued early; consumed only at the tail
  uint2 ps = *(const uint2*)(xlbase + ((unsigned)(n * 512) + cbb));

  float4 xr4 = bf2f4(*(const uint2*)&xrb_[(size_t)n * HF + cb]);
  float4 at4 = *(const float4*)&att[cb];
  float4 w04 = *(const float4*)&We[cb];
  float4 w14 = *(const float4*)&We[HF + cb];
  f32x2 xrA = {xr4.x, xr4.y}, xrB = {xr4.z, xr4.w};
  f32x2 atA = {at4.x, at4.y}, atB = {at4.z, at4.w};
  f32x2 w0A = {w04.x, w04.y}, w0B = {w04.z, w04.w};
  f32x2 w1A = {w14.x, w14.y}, w1B = {w14.z, w14.w};

  f32x2 accA = {0.f, 0.f}, accB = {0.f, 0.f};
  float den = 0.f;

  // ---- guard-free main loop: full batches of 4 real edges ----
  int nfull = nreal >> 2;
  for (int bb = 0; bb < nfull; ++bb) {
    int e0 = bb << 2;
    uint4 q0 = *(const uint4*)&recn[e0];         // records e0, e0+1 (real)
    uint4 q1 = *(const uint4*)&recn[e0 + 2];     // records e0+2, e0+3 (real)
    unsigned off[4] = {q0.x, q0.z, q1.x, q1.z};
    unsigned atr[4] = {q0.y, q0.w, q1.y, q1.w};
    uint2 p4[4];
#pragma unroll
    for (int i = 0; i < 4; ++i)
      p4[i] = *(const uint2*)(xlbase + (off[i] + cbb));   // no clamp: offsets valid

    float t4[4];
#pragma unroll
    for (int i = 0; i < 4; ++i) {
      float a0 = __uint_as_float(atr[i] << 16);
      float a1 = __uint_as_float(atr[i] & 0xffff0000u);
      f32x2 a0v = {a0, a0}, a1v = {a1, a1};
      f32x2 mA = a1v * w1A + xrA; mA = a0v * w0A + mA; // pk_fma chains
      f32x2 mB = a1v * w1B + xrB; mB = a0v * w0B + mB;
      mA = lky(mA + bflo2(p4[i].x));
      mB = lky(mB + bflo2(p4[i].y));
      f32x2 d = mA * atA;
      d = mB * atB + d;
      t4[i] = d.x + d.y;
    }
#pragma unroll
    for (int i = 0; i < 4; ++i) t4[i] = row_sum16(t4[i]);   // DPP, 4 indep chains
#pragma unroll
    for (int i = 0; i < 4; ++i) {
      float w = __expf(t4[i]);                   // no clamp/mask: real edge, |t|~O(5)
      den += w;
      f32x2 wv = {w, w};
      accA = wv * bflo2(p4[i].x) + accA;         // pk_fma
      accB = wv * bflo2(p4[i].y) + accB;
    }
  }

  // ---- masked epilogue: remaining 1..3 edges (clamped indices -> real records) ----
  int rem = nreal & 3;
  if (rem) {
    int e0 = nfull << 2;
    uint2 r4[4], p4[4];
#pragma unroll
    for (int i = 0; i < 4; ++i)
      r4[i] = recn[min(e0 + i, lastE)];          // real record (duplicate past rem)
#pragma unroll
    for (int i = 0; i < 4; ++i)
      p4[i] = *(const uint2*)(xlbase + (r4[i].x + cbb));

    float t4[4];
#pragma unroll
    for (int i = 0; i < 4; ++i) {
      float a0 = __uint_as_float(r4[i].y << 16);
      float a1 = __uint_as_float(r4[i].y & 0xffff0000u);
      f32x2 a0v = {a0, a0}, a1v = {a1, a1};
      f32x2 mA = a1v * w1A + xrA; mA = a0v * w0A + mA;
      f32x2 mB = a1v * w1B + xrB; mB = a0v * w0B + mB;
      mA = lky(mA + bflo2(p4[i].x));
      mB = lky(mB + bflo2(p4[i].y));
      f32x2 d = mA * atA;
      d = mB * atB + d;
      t4[i] = d.x + d.y;
    }
#pragma unroll
    for (int i = 0; i < 4; ++i) t4[i] = row_sum16(t4[i]);
#pragma unroll
    for (int i = 0; i < 4; ++i) {
      float w = (i < rem) ? __expf(t4[i]) : 0.f;  // mask duplicates
      den += w;
      f32x2 wv = {w, w};
      accA = wv * bflo2(p4[i].x) + accA;
      accB = wv * bflo2(p4[i].y) + accB;
    }
  }

  // ---- mean-attr reduction: DPP within rows, shfl across rows (once/node) ----
  a0s = row_sum16(a0s);
  a1s = row_sum16(a1s);
  a0s += __shfl_xor(a0s, 16, 64);
  a1s += __shfl_xor(a1s, 16, 64);
  a0s += __shfl_xor(a0s, 32, 64);
  a1s += __shfl_xor(a1s, 32, 64);
  float im = 1.0f / fmaxf((float)nreal, 1.0f);
  float a0m = a0s * im, a1m = a1s * im;

  // ---- self-loop term (attrs = mean of incoming), added last ----
  f32x2 vSA = bflo2(ps.x), vSB = bflo2(ps.y);
  {
    f32x2 a0v = {a0m, a0m}, a1v = {a1m, a1m};
    f32x2 mA = a1v * w1A + xrA; mA = a0v * w0A + mA;
    f32x2 mB = a1v * w1B + xrB; mB = a0v * w0B + mB;
    mA = lky(mA + vSA);
    mB = lky(mB + vSB);
    f32x2 d = mA * atA;
    d = mB * atB + d;
    float tS = row_sum16(d.x + d.y);
    float wS = __expf(fminf(tS, 80.f));
    den += wS;
    f32x2 wv = {wS, wS};
    accA = wv * vSA + accA;
    accB = wv * vSB + accB;
  }

  float inv = 1.0f / den;
  float4 b4 = *(const float4*)&bias[cb];
  float4 o;
  o.x = fmaf(accA.x, inv, b4.x);
  o.y = fmaf(accA.y, inv, b4.y);
  o.z = fmaf(accB.x, inv, b4.z);
  o.w = fmaf(accB.y, inv, b4.w);
  o.x = (o.x > 0.f) ? o.x : expm1f(o.x);            // elu
  o.y = (o.y > 0.f) ? o.y : expm1f(o.y);
  o.z = (o.z > 0.f) ? o.z : expm1f(o.z);
  o.w = (o.w > 0.f) ? o.w : expm1f(o.w);

  if (L0) {
    f32x2 rA = {0.f, 0.f}, rB = {0.f, 0.f};
#pragma unroll
    for (int k = 0; k < INF_; ++k) {
      float xv = x[n * INF_ + k];                    // wave-uniform -> scalar load
      float4 p = *(const float4*)&proj0[k * HF + cb];
      f32x2 xvv = {xv, xv};
      f32x2 pA = {p.x, p.y}, pB = {p.z, p.w};
      rA = xvv * pA + rA;
      rB = xvv * pB + rB;
    }
    o.x += rA.x; o.y += rA.y; o.z += rB.x; o.w += rB.y;
    uint2 pk;                          // x1 kept only as bf16 (feeds MFMA + residual)
    pk.x = (unsigned)f2bf(o.x) | ((unsigned)f2bf(o.y) << 16);
    pk.y = (unsigned)f2bf(o.z) | ((unsigned)f2bf(o.w) << 16);
    *(uint2*)&x1bout[(size_t)n * HF + cb] = pk;
  } else {
    float4 x1v = bf2f4(*(const uint2*)&x1bin[(size_t)n * HF + cb]);
    o.x += x1v.x; o.y += x1v.y; o.z += x1v.z; o.w += x1v.w;
    uint2 pk;                          // x2 bf16 (feeds mean-pool; error attenuated ~17x)
    pk.x = (unsigned)f2bf(o.x) | ((unsigned)f2bf(o.y) << 16);
    pk.y = (unsigned)f2bf(o.z) | ((unsigned)f2bf(o.w) << 16);
    *(uint2*)&x2bout[(size_t)n * HF + cb] = pk;      // aliases xrb_ row n: safe (own row, after read)
  }
}

// ---------------- pre-pool MLP + graph pooling: z=elu(x2@Wp+bp); gpool += z ----------------

__global__ __launch_bounds__(256) void k_pool(
    const unsigned short* __restrict__ x2b, const float* __restrict__ Wp,
    const float* __restrict__ bp, const int* __restrict__ batch,
    float* __restrict__ gpool, int* __restrict__ gcnt) {
  __shared__ float xs[32 * HF];
  __shared__ int gid_s[32];
  int t = threadIdx.x;
  int row0 = blockIdx.x * 32;
  // stage 32 rows x 256 cols bf16 -> fp32 LDS (unpack once)
  const uint4* s4 = (const uint4*)(x2b + (size_t)row0 * HF);  // uint4 = 8 bf16
#pragma unroll
  for (int i = 0; i < 4; ++i) {
    int idx = i * 256 + t;               // 0..1023 (32*256/8)
    uint4 p = s4[idx];
    int base = idx * 8;
    float4 lo = bf2f4(make_uint2(p.x, p.y));
    float4 hi = bf2f4(make_uint2(p.z, p.w));
    *(float4*)&xs[base] = lo;
    *(float4*)&xs[base + 4] = hi;
  }
  if (t < 32) gid_s[t] = batch[row0 + t];
  __syncthreads();
  int j = t & 63, rg = t >> 6;          // thread: col j, rows rg*8..rg*8+7
  float acc[8];
#pragma unroll
  for (int rr = 0; rr < 8; ++rr) acc[rr] = 0.f;
  for (int k4 = 0; k4 < HF / 4; ++k4) {
    float w0 = Wp[(k4 * 4 + 0) * FCD + j];
    float w1 = Wp[(k4 * 4 + 1) * FCD + j];
    float w2 = Wp[(k4 * 4 + 2) * FCD + j];
    float w3 = Wp[(k4 * 4 + 3) * FCD + j];
#pragma unroll
    for (int rr = 0; rr < 8; ++rr) {
      float4 xv = *(const float4*)&xs[(rg * 8 + rr) * HF + k4 * 4];
      acc[rr] = fmaf(xv.x, w0, acc[rr]);
      acc[rr] = fmaf(xv.y, w1, acc[rr]);
      acc[rr] = fmaf(xv.z, w2, acc[rr]);
      acc[rr] = fmaf(xv.w, w3, acc[rr]);
    }
  }
  float b = bp[j];
  int gprev = gid_s[rg * 8];
  float run = 0.f;
  int rcnt = 0;
#pragma unroll
  for (int rr = 0; rr < 8; ++rr) {
    float a = acc[rr] + b;
    float z = (a > 0.f) ? a : expm1f(a);
    int g = gid_s[rg * 8 + rr];
    if (g != gprev) {
      atomicAdd(&gpool[gprev * FCD + j], run);
      if (j == 0) atomicAdd(&gcnt[gprev], rcnt);
      run = 0.f; rcnt = 0; gprev = g;
    }
    run += z; ++rcnt;
  }
  atomicAdd(&gpool[gprev * FCD + j], run);
  if (j == 0) atomicAdd(&gcnt[gprev], rcnt);
}

// ---------------- final classifier (wave-parallel): one wave per graph ----------------

__global__ __launch_bounds__(256) void k_head(
    const float* __restrict__ gpool, const int* __restrict__ gcnt,
    const float* __restrict__ Wc, const float* __restrict__ bc,
    float* __restrict__ out) {
  int g = (blockIdx.x << 2) + (threadIdx.x >> 6);   // 0..63
  int lane = threadIdx.x & 63;
  float v = gpool[g * FCD + lane] / fmaxf((float)gcnt[g], 1.0f);
  float2 wc = *(const float2*)&Wc[lane * NCD];
  float a0 = v * wc.x, a1 = v * wc.y;
#pragma unroll
  for (int o = 32; o; o >>= 1) {
    a0 += __shfl_xor(a0, o, 64);
    a1 += __shfl_xor(a1, o, 64);
  }
  if (lane == 0) {
    float2 r = make_float2(a0 + bc[0], a1 + bc[1]);
    *(float2*)&out[g * NCD] = r;
  }
}

// ---------------- launch ----------------

extern "C" void kernel_launch(void* const* d_in, const int* in_sizes, int n_in,
                              void* d_out, int out_size, void* d_ws, size_t ws_size,
                              hipStream_t stream) {
  const float* x    = (const float*)d_in[0];
  const int*   ei   = (const int*)d_in[1];    // [2,E] int
  const float* ea   = (const float*)d_in[2];  // [E,2]
  const int*   batch= (const int*)d_in[3];
  const float* Wl0  = (const float*)d_in[4];
  const float* bl0  = (const float*)d_in[5];
  const float* Wr0  = (const float*)d_in[6];
  const float* br0  = (const float*)d_in[7];
  const float* We0  = (const float*)d_in[8];
  const float* att0 = (const float*)d_in[9];
  const float* b0   = (const float*)d_in[10];
  const float* proj0= (const float*)d_in[11];
  const float* Wl1  = (const float*)d_in[12];
  const float* bl1  = (const float*)d_in[13];
  const float* Wr1  = (const float*)d_in[14];
  const float* br1  = (const float*)d_in[15];
  const float* We1  = (const float*)d_in[16];
  const float* att1 = (const float*)d_in[17];
  const float* b1   = (const float*)d_in[18];
  const float* Wp   = (const float*)d_in[19];
  const float* bp   = (const float*)d_in[20];
  const float* Wc   = (const float*)d_in[21];
  const float* bc   = (const float*)d_in[22];
  float* out = (float*)d_out;

  // workspace layout (all 16B aligned)
  char* ws = (char*)d_ws;
  size_t off = 0;
  int*   cnt    = (int*)(ws + off);   off += (NN * 4 + 15) / 16 * 16;
  uint2* rec    = (uint2*)(ws + off); off += (size_t)NN * CAP * 8;     // 10.24 MB
  unsigned short* xlb = (unsigned short*)(ws + off); off += (size_t)NN * HF * 2;
  unsigned short* xrb = (unsigned short*)(ws + off); off += (size_t)NN * HF * 2;
  unsigned short* x1b = (unsigned short*)(ws + off); off += (size_t)NN * HF * 2;
  float* gpool  = (float*)(ws + off); off += NG * FCD * 4;
  unsigned short* Wsw = (unsigned short*)(ws + off); off += 512 * 256 * 2;
  int*   gcnt   = (int*)(ws + off);   off += (NG * 4 + 15) / 16 * 16;
  unsigned short* x2b = xrb;           // alias: safe (each wave writes only its own row, after reading it)
  (void)ws_size; (void)in_sizes; (void)n_in; (void)out_size;

  // init (zero cnt|gpool|gcnt, wconv, l0) -- one dispatch, no memsets
  k_init<<<ZB + 1 + WCB + L0B, 256, 0, stream>>>(
      cnt, gpool, gcnt, Wl1, Wr1, Wsw, x, Wl0, bl0, Wr0, br0, xlb, xrb);

  // fused count+scatter into fixed-capacity buckets (no CSR scan)
  k_scatter<<<(NE + 255) / 256, 256, 0, stream>>>(ei, ea, cnt, rec);

  // layer 0 aggregation (self-loop mean folded into warm pass)
  k_agg<true><<<(NN * 64 + 255) / 256, 256, 0, stream>>>(
      xlb, xrb, cnt, rec, att0, We0, b0, x, proj0, x1b, nullptr, nullptr);

  // layer 1 transforms via MFMA (y=0: Wl->xlb, y=1: Wr->xrb), then aggregation
  k_l1_mfma<<<dim3((NN + 63) / 64, 2), 256, 0, stream>>>(x1b, Wsw, bl1, br1, xlb, xrb);
  k_agg<false><<<(NN * 64 + 255) / 256, 256, 0, stream>>>(
      xlb, xrb, cnt, rec, att1, We1, b1, nullptr, nullptr, nullptr, x1b, x2b);

  // pre-pool MLP + pooling (also accumulates per-graph node counts), then classifier
  k_pool<<<NN / 32, 256, 0, stream>>>(x2b, Wp, bp, batch, gpool, gcnt);
  k_head<<<16, 256, 0, stream>>>(gpool, gcnt, Wc, bc, out);
}